// Round 7
// baseline (249.859 us; speedup 1.0000x reference)
//
#include <hip/hip_runtime.h>
#include <math.h>

// MoE router: X[8192,4096] fp32 @ W^T[4096,64] -> logits -> top2 softmax scatter.
// d_out = probs[8192*64] ++ routing_map[8192*64] (floats).
//
// R1: lane=token raw X reads -> 4x overfetch. Fixed via LDS staging.
// R2: 96us; VALU-busy TIME == 27.3us fp32-FMA floor, duty 30% (SMEM drain).
// R3 FAILED: >64 acc VGPRs -> scratch. R4 FAILED: W b128-broadcast floods LDS pipe.
// R5: 8x8 reg-tile outer product, 90us, duty 41%.
// R6 FAILED: 2x waves/CU changed NOTHING -> limiter is the shared per-CU LDS
//     pipe (4 b128 / 128 FMA-cyc per SIMD x4 = 150% oversubscribed). Any
//     LDS-fed fp32 outer product caps ~41% duty. Escape via the MFMA pipe:
// R7: f16 split-MFMA (x = xh+xl, w = wh+wl; 3 products hh+hl+lh), X scaled
//     2^11, W 2^10 (exact; kills f16 denormals; undone 2^-21 at epilogue).
//     Dropped ll term ~2^-22 -> logits err ~2e-7 << top-2/3 gaps (~0.3).
//     A/B frags register-direct from global (no K-loop LDS). Fused epilogue:
//     LDS reduce + wave top-2 + direct output (part array + topk kernel gone).
//
// ws: Wh[64][4096] f16 | Wl[64][4096] f16 (1MB total; L2-resident).

#define HDIM 4096
#define NEXP 64
#define NTOK 8192

typedef __attribute__((ext_vector_type(8))) _Float16 half8;
typedef __attribute__((ext_vector_type(4))) float  f32x4;

// ---------------- kernel 0: split W -> (Wh, Wl) f16, scaled by 2^10 ----------------
__global__ __launch_bounds__(256) void wprep_kernel(
        const float* __restrict__ W,
        _Float16* __restrict__ Wh, _Float16* __restrict__ Wl) {
    int i = blockIdx.x * 256 + threadIdx.x;        // grid 1024 -> 262144
    float w = W[i] * 1024.f;
    _Float16 h = (_Float16)w;
    Wh[i] = h;
    Wl[i] = (_Float16)(w - (float)h);
}

// ---------------- kernel 1: fused logits + top-2 softmax + scatter ----------------
// block = 256 (4 waves), 16 tokens; wave wv covers k in [wv*1024, wv*1024+1024).
__global__ __launch_bounds__(256) void router_kernel(
        const float* __restrict__ X, const _Float16* __restrict__ Wh,
        const _Float16* __restrict__ Wl,
        float* __restrict__ probs, float* __restrict__ rmap) {
    const int lane = threadIdx.x & 63;
    const int wv   = threadIdx.x >> 6;     // 0..3 = k-split
    const int m    = lane & 15;            // A row / B col / D col selector
    const int q    = lane >> 4;            // 0..3 quad
    const int t0   = blockIdx.x * 16;      // token tile base

    __shared__ float part_s[4][16][68];    // pad 68: reduce reads 2-way (free)

    f32x4 acc[4];                          // 4 expert tiles (n*16), D-layout
    #pragma unroll
    for (int n = 0; n < 4; ++n) acc[n] = (f32x4){0.f, 0.f, 0.f, 0.f};

    const int kbase = wv * (HDIM / 4);
    const float* xrow = X + (size_t)(t0 + m) * HDIM;

    // double-buffered register pipeline; all loads direct from global.
    float4 xbuf[2][2];
    half8  whb[2][4], wlb[2][4];

    auto loadstep = [&](int s, int b) {
        const int k = kbase + s * 32 + q * 8;
        const float* xp = xrow + k;
        xbuf[b][0] = *reinterpret_cast<const float4*>(xp);
        xbuf[b][1] = *reinterpret_cast<const float4*>(xp + 4);
        #pragma unroll
        for (int n = 0; n < 4; ++n) {
            size_t wo = (size_t)(n * 16 + m) * HDIM + k;   // e-major, k-contig
            whb[b][n] = *reinterpret_cast<const half8*>(Wh + wo);
            wlb[b][n] = *reinterpret_cast<const half8*>(Wl + wo);
        }
    };

    loadstep(0, 0);
    #pragma unroll 2
    for (int s = 0; s < 32; ++s) {
        const int b = s & 1;
        if (s + 1 < 32) loadstep(s + 1, 1 - b);    // prefetch next k-step

        // split-convert A fragment: 8 fp32 -> (ah, al) f16, scaled 2^11
        float xv[8] = {xbuf[b][0].x, xbuf[b][0].y, xbuf[b][0].z, xbuf[b][0].w,
                       xbuf[b][1].x, xbuf[b][1].y, xbuf[b][1].z, xbuf[b][1].w};
        half8 ah, al;
        #pragma unroll
        for (int j = 0; j < 8; ++j) {
            float xs = xv[j] * 2048.f;
            _Float16 h = (_Float16)xs;
            ah[j] = h;
            al[j] = (_Float16)(xs - (float)h);
        }
        // 3-product split accumulation (hh + hl + lh), 12 MFMA per k-step
        #pragma unroll
        for (int n = 0; n < 4; ++n) {
            acc[n] = __builtin_amdgcn_mfma_f32_16x16x32_f16(ah, whb[b][n], acc[n], 0, 0, 0);
            acc[n] = __builtin_amdgcn_mfma_f32_16x16x32_f16(ah, wlb[b][n], acc[n], 0, 0, 0);
            acc[n] = __builtin_amdgcn_mfma_f32_16x16x32_f16(al, whb[b][n], acc[n], 0, 0, 0);
        }
    }

    // D-layout: token row = q*4 + r, expert col = n*16 + m
    #pragma unroll
    for (int n = 0; n < 4; ++n)
        #pragma unroll
        for (int r = 0; r < 4; ++r)
            part_s[wv][q * 4 + r][n * 16 + m] = acc[n][r];
    __syncthreads();

    // top-2 softmax scatter: wave wv handles tokens wv*4..wv*4+3; lane = expert
    const float inv = 1.f / (2048.f * 1024.f);     // undo exact pow-2 scaling
    #pragma unroll
    for (int tt = 0; tt < 4; ++tt) {
        const int tok = wv * 4 + tt;
        float v = (part_s[0][tok][lane] + part_s[1][tok][lane] +
                   part_s[2][tok][lane] + part_s[3][tok][lane]) * inv;

        // top-1 (lower index wins ties, like lax.top_k)
        float m1 = v; int i1 = lane;
        #pragma unroll
        for (int sft = 32; sft > 0; sft >>= 1) {
            float om = __shfl_xor(m1, sft, 64);
            int   oi = __shfl_xor(i1, sft, 64);
            if (om > m1 || (om == m1 && oi < i1)) { m1 = om; i1 = oi; }
        }
        // top-2: exclude i1
        float vx = (lane == i1) ? -INFINITY : v;
        float m2 = vx; int i2 = lane;
        #pragma unroll
        for (int sft = 32; sft > 0; sft >>= 1) {
            float om = __shfl_xor(m2, sft, 64);
            int   oi = __shfl_xor(i2, sft, 64);
            if (om > m2 || (om == m2 && oi < i2)) { m2 = om; i2 = oi; }
        }

        float e2 = expf(m2 - m1);                  // m2 <= m1: safe
        float p1 = 1.f / (1.f + e2);
        float p2 = 1.f - p1;

        float prob = (lane == i1) ? p1 : ((lane == i2) ? p2 : 0.f);
        float flag = (lane == i1 || lane == i2) ? 1.f : 0.f;
        probs[(size_t)(t0 + tok) * NEXP + lane] = prob;   // coalesced
        rmap [(size_t)(t0 + tok) * NEXP + lane] = flag;
    }
}

extern "C" void kernel_launch(void* const* d_in, const int* in_sizes, int n_in,
                              void* d_out, int out_size, void* d_ws, size_t ws_size,
                              hipStream_t stream) {
    const float* X = (const float*)d_in[0];   // [8192,4096]
    const float* W = (const float*)d_in[1];   // [64,4096]
    float* out = (float*)d_out;

    _Float16* Wh = (_Float16*)d_ws;                       // 262144 halves
    _Float16* Wl = Wh + (size_t)NEXP * HDIM;              // 262144 halves

    wprep_kernel<<<(NEXP * HDIM) / 256, 256, 0, stream>>>(W, Wh, Wl);
    router_kernel<<<NTOK / 16, 256, 0, stream>>>(X, Wh, Wl,
                                                 out, out + (size_t)NTOK * NEXP);
}